// Round 11
// baseline (143.655 us; speedup 1.0000x reference)
//
#include <hip/hip_runtime.h>
#include <stdint.h>
#include <stddef.h>

#define Tdim 4096
#define Hdim 2048

typedef short short8 __attribute__((ext_vector_type(8)));
typedef float floatx4 __attribute__((ext_vector_type(4)));

// RNE fp32 -> bf16 bit pattern
__device__ __forceinline__ unsigned short f2bf(float f) {
  uint32_t u = __float_as_uint(f);
  u += 0x7fffu + ((u >> 16) & 1u);
  return (unsigned short)(u >> 16);
}

// async global->LDS, 16B per lane. LDS dest is wave-uniform base + lane*16.
__device__ __forceinline__ void load_lds16(const void* g, void* l) {
  __builtin_amdgcn_global_load_lds(
      (__attribute__((address_space(1))) unsigned int*)(uintptr_t)g,
      (__attribute__((address_space(3))) unsigned int*)l,
      16, 0, 0);
}

__device__ __forceinline__ float tanh_fast(float z) {
  // tanh(z) = 1 - 2/(exp(2z)+1); safe for all z
  float e = __expf(z + z);
  return 1.0f - __fdividef(2.0f, e + 1.0f);
}

// aligned LDS vector read (forces ds_read_b128)
__device__ __forceinline__ short8 lds_read8(const unsigned short* p) {
  return *(const short8*)__builtin_assume_aligned(p, 16);
}

// ---- fused convert: blocks [0,4096) cast x -> bf16; blocks [4096,5120)
// transpose+cast b (HxH fp32, [k][n]) -> bt bf16 (N x K, [n][k]) ----
__global__ __launch_bounds__(256) void cvt_kernel(const float* __restrict__ x,
                                                  const float* __restrict__ b,
                                                  unsigned short* __restrict__ xbf,
                                                  unsigned short* __restrict__ bt) {
  __shared__ unsigned short tile[64 * 65];
  const int t = threadIdx.x;
  if (blockIdx.x < 4096) {
    size_t i = ((size_t)blockIdx.x * 256 + t) * 8;
    float4 f0 = *(const float4*)(x + i);
    float4 f1 = *(const float4*)(x + i + 4);
    union { unsigned short u[8]; uint4 v; } o;
    o.u[0] = f2bf(f0.x); o.u[1] = f2bf(f0.y); o.u[2] = f2bf(f0.z); o.u[3] = f2bf(f0.w);
    o.u[4] = f2bf(f1.x); o.u[5] = f2bf(f1.y); o.u[6] = f2bf(f1.z); o.u[7] = f2bf(f1.w);
    *(uint4*)(xbf + i) = o.v;
    return;
  }
  const int tb = blockIdx.x - 4096;
  const int bj = tb & 31;  // n block
  const int bi = tb >> 5;  // k block
  {
    const int r0 = t >> 4, c4 = (t & 15) * 4;
#pragma unroll
    for (int p = 0; p < 4; ++p) {
      int r = r0 + p * 16;
      float4 v = *(const float4*)(b + (size_t)(bi * 64 + r) * Hdim + bj * 64 + c4);
      tile[r * 65 + c4 + 0] = f2bf(v.x);
      tile[r * 65 + c4 + 1] = f2bf(v.y);
      tile[r * 65 + c4 + 2] = f2bf(v.z);
      tile[r * 65 + c4 + 3] = f2bf(v.w);
    }
  }
  __syncthreads();
  {
    const int n = t >> 2, kq = (t & 3) * 16;
    union { unsigned short u[16]; uint4 v[2]; } o;
#pragma unroll
    for (int q = 0; q < 16; ++q) o.u[q] = tile[(kq + q) * 65 + n];
    uint4* dst = (uint4*)(bt + (size_t)(bj * 64 + n) * Hdim + bi * 64 + kq);
    dst[0] = o.v[0];
    dst[1] = o.v[1];
  }
}

// ---- GEMM (s = x @ b) with fused windowed-scan epilogue ----
// 128x128 tile, BK=128, 4 waves 2x2 of 64x64 (4x4 frags of 16x16x32 MFMA).
//
// LDS swizzle (round 11: FULL 4-bit XOR): slot (row, chunk c) holds global
// chunk c ^ (row&15). BK=128 has 16 chunks/row; round-10's 3-bit XOR made
// lanes l15 and l15^8 of a quad collide (4-way conflicts, 4.7e6 counted).
// Fragment rows have row&15 == l15 and staging rows advance 16/issue, so
// the 4-bit term is consistent on both sides; a quad's 16 lanes now read
// 16 distinct 16B chunks spanning exactly 2 bank rows -> 2-way = free.
//
// BK=128 halves the barrier/drain count (32 -> 16) at zero occupancy cost
// (LDS already dominated by the 68.5KB s_tile union; grid forces 2 bl/CU).
// XCD swizzle: grid (bm=32 fastest, bn=16) so XCD = bm%8; per-XCD A working
// set 2MB, L2-resident (FETCH 69.7 -> 41.5 MB, r9).
//
// Warm rows: 8 extra A rows (t0-8..t0-1) so the scan warms up in-block
// (|a| <= 0.03125 -> influence of h_{t-8} < 1e-12); warm frag+MFMA on
// waves 0,1 only. Epilogue: acc -> s_tile (136x129 fp32) -> 256 threads
// scan 128 cols x 2 half-chunks -> out. No s buffer in HBM.
__global__ __launch_bounds__(256) void gemm_scan_kernel(const unsigned short* __restrict__ A,
                                                        const unsigned short* __restrict__ Bt,
                                                        const float* __restrict__ a_mat,
                                                        float* __restrict__ out) {
  // alignas(16) REQUIRED: otherwise union alignment is 4 and short8 LDS
  // reads split into 4x ds_read_b32 with 16-way conflicts (round-2: 263 us).
  __shared__ alignas(16) union SM {
    struct {
      unsigned short sA[128 * 128];   // 32 KB
      unsigned short sB[128 * 128];   // 32 KB
      unsigned short sAw[8 * 128];    // 2 KB
    } st;                      // 66 KB
    float s_tile[136 * 129];   // 68.5 KB; [row][col], pad 129
  } sm;

  const int tid = threadIdx.x;
  const int bm = blockIdx.x, bn = blockIdx.y;  // bm fastest -> XCD = bm%8
  const int wave = tid >> 6, lane = tid & 63;
  const int wm = (wave >> 1) * 64, wn = (wave & 1) * 64;
  const int l15 = lane & 15, quad = lane >> 4;
  const int l7 = l15 & 7;

  // staging: thread tid fills LDS slot (row = 16c + (tid>>4), chunk = tid&15)
  // and fetches global chunk (tid&15) ^ (tid>>4)  [= chunk ^ (row&15), since
  // rows advance 16 per issue]. 4-bit XOR matches the fragment-read swizzle.
  const int swz = ((tid & 15) ^ (tid >> 4)) * 8;
  const unsigned short* aSrc = A + ((size_t)(bm * 128 + (tid >> 4)) * Hdim + swz);
  const unsigned short* bSrc = Bt + ((size_t)(bn * 128 + (tid >> 4)) * Hdim + swz);
  // warm rows (0..7; row&15 == row&7 there) staged by wave 3 in two issues
  // of 4 rows; per-issue XOR term since 4 !≡ 0 mod 8.
  const int tw0 = (bm > 0) ? bm * 128 - 8 : 0;  // clamp keeps address valid; bm==0 warm unused
  const int wrow0 = lane >> 4;  // 0..3
  const unsigned short* wSrc0 =
      A + ((size_t)(tw0 + wrow0) * Hdim + ((lane & 15) ^ wrow0) * 8);
  const unsigned short* wSrc1 =
      A + ((size_t)(tw0 + 4 + wrow0) * Hdim + ((lane & 15) ^ (4 + wrow0)) * 8);
  unsigned short* aDst = &sm.st.sA[tid * 8];
  unsigned short* bDst = &sm.st.sB[tid * 8];
  unsigned short* wDst = &sm.st.sAw[lane * 8];

  floatx4 acc[4][4] = {};
  floatx4 accw[4] = {};

  for (int k0 = 0; k0 < Hdim; k0 += 128) {
#pragma unroll
    for (int c = 0; c < 8; ++c)
      load_lds16(aSrc + (size_t)c * 16 * Hdim + k0, aDst + c * 2048);
#pragma unroll
    for (int c = 0; c < 8; ++c)
      load_lds16(bSrc + (size_t)c * 16 * Hdim + k0, bDst + c * 2048);
    if (wave == 3) {
      load_lds16(wSrc0 + k0, wDst);
      load_lds16(wSrc1 + k0, wDst + 512);
    }
    __syncthreads();
#pragma unroll
    for (int kk = 0; kk < 128; kk += 32) {
      // global chunk g = kk/8 + quad (0..15); slot chunk = g ^ (row&15),
      // and fragment rows have row&15 == l15.
      const int coff = (((kk >> 3) + quad) ^ l15) * 8;
      const int coffw = (((kk >> 3) + quad) ^ l7) * 8;  // warm rows: row&15 = l7
      short8 av[4], bv[4];
#pragma unroll
      for (int i = 0; i < 4; ++i)
        av[i] = lds_read8(&sm.st.sA[(wm + i * 16 + l15) * 128 + coff]);
#pragma unroll
      for (int j = 0; j < 4; ++j)
        bv[j] = lds_read8(&sm.st.sB[(wn + j * 16 + l15) * 128 + coff]);
#pragma unroll
      for (int i = 0; i < 4; ++i)
#pragma unroll
        for (int j = 0; j < 4; ++j)
          acc[i][j] = __builtin_amdgcn_mfma_f32_16x16x32_bf16(av[i], bv[j], acc[i][j], 0, 0, 0);
      if (wave < 2) {  // warm rows: frag read + MFMA on waves 0,1 only
        short8 aw = lds_read8(&sm.st.sAw[l7 * 128 + coffw]);
#pragma unroll
        for (int j = 0; j < 4; ++j)
          accw[j] = __builtin_amdgcn_mfma_f32_16x16x32_bf16(aw, bv[j], accw[j], 0, 0, 0);
      }
    }
    __syncthreads();
  }

  // ---- epilogue: registers -> s_tile (C/D layout: col=lane&15, row=quad*4+r) ----
  if (wave < 2 && quad < 2) {  // warm rows idx 0..7 (valid m = 0..7 only)
#pragma unroll
    for (int j = 0; j < 4; ++j)
#pragma unroll
      for (int r = 0; r < 4; ++r)
        sm.s_tile[(quad * 4 + r) * 129 + wn + j * 16 + l15] = accw[j][r];
  }
#pragma unroll
  for (int i = 0; i < 4; ++i)
#pragma unroll
    for (int j = 0; j < 4; ++j)
#pragma unroll
      for (int r = 0; r < 4; ++r)
        sm.s_tile[(8 + wm + i * 16 + quad * 4 + r) * 129 + wn + j * 16 + l15] = acc[i][j][r];
  __syncthreads();

  // ---- windowed scan: 256 threads = 128 cols x 2 half-chunks of 64 rows ----
  const int col = tid & 127;
  const int half = tid >> 7;
  const float aj = a_mat[bn * 128 + col];
  float h = 0.0f;
  const int row0 = 8 + half * 64;
  if (!(bm == 0 && half == 0)) {
#pragma unroll
    for (int r = row0 - 8; r < row0; ++r)  // warm-up (discarded outputs)
      h = tanh_fast(fmaf(aj, h, sm.s_tile[r * 129 + col]));
  }
  const size_t gbase = (size_t)(bm * 128 + half * 64) * Hdim + bn * 128 + col;
#pragma unroll 4
  for (int r2 = 0; r2 < 64; ++r2) {
    h = tanh_fast(fmaf(aj, h, sm.s_tile[(row0 + r2) * 129 + col]));
    out[gbase + (size_t)r2 * Hdim] = h;
  }
}

extern "C" void kernel_launch(void* const* d_in, const int* in_sizes, int n_in,
                              void* d_out, int out_size, void* d_ws, size_t ws_size,
                              hipStream_t stream) {
  const float* x = (const float*)d_in[0];
  const float* a = (const float*)d_in[1];
  const float* b = (const float*)d_in[2];
  float* out = (float*)d_out;

  unsigned short* ws = (unsigned short*)d_ws;
  unsigned short* xbf = ws;                                 // 16.8 MB
  unsigned short* btb = xbf + (size_t)Tdim * Hdim;          // 8.4 MB

  hipLaunchKernelGGL(cvt_kernel, dim3(4096 + (Hdim / 64) * (Hdim / 64)), dim3(256), 0, stream,
                     x, b, xbf, btb);
  // grid: x = bm (32, fastest -> XCD = bm%8), y = bn (16)
  hipLaunchKernelGGL(gemm_scan_kernel, dim3(Tdim / 128, Hdim / 128), dim3(256), 0, stream,
                     xbf, btb, a, out);
}

// Round 12
// 141.715 us; speedup vs baseline: 1.0137x; 1.0137x over previous
//
#include <hip/hip_runtime.h>
#include <stdint.h>
#include <stddef.h>

#define Tdim 4096
#define Hdim 2048

typedef short short8 __attribute__((ext_vector_type(8)));
typedef float floatx4 __attribute__((ext_vector_type(4)));

// RNE fp32 -> bf16 bit pattern
__device__ __forceinline__ unsigned short f2bf(float f) {
  uint32_t u = __float_as_uint(f);
  u += 0x7fffu + ((u >> 16) & 1u);
  return (unsigned short)(u >> 16);
}

// async global->LDS, 16B per lane. LDS dest is wave-uniform base + lane*16.
__device__ __forceinline__ void load_lds16(const void* g, void* l) {
  __builtin_amdgcn_global_load_lds(
      (__attribute__((address_space(1))) unsigned int*)(uintptr_t)g,
      (__attribute__((address_space(3))) unsigned int*)l,
      16, 0, 0);
}

__device__ __forceinline__ float tanh_fast(float z) {
  // tanh(z) = 1 - 2/(exp(2z)+1); safe for all z
  float e = __expf(z + z);
  return 1.0f - __fdividef(2.0f, e + 1.0f);
}

// aligned LDS vector read (forces ds_read_b128)
__device__ __forceinline__ short8 lds_read8(const unsigned short* p) {
  return *(const short8*)__builtin_assume_aligned(p, 16);
}

// ---- fused convert: blocks [0,4096) cast x -> bf16; blocks [4096,5120)
// transpose+cast b (HxH fp32, [k][n]) -> bt bf16 (N x K, [n][k]) ----
__global__ __launch_bounds__(256) void cvt_kernel(const float* __restrict__ x,
                                                  const float* __restrict__ b,
                                                  unsigned short* __restrict__ xbf,
                                                  unsigned short* __restrict__ bt) {
  __shared__ unsigned short tile[64 * 65];
  const int t = threadIdx.x;
  if (blockIdx.x < 4096) {
    size_t i = ((size_t)blockIdx.x * 256 + t) * 8;
    float4 f0 = *(const float4*)(x + i);
    float4 f1 = *(const float4*)(x + i + 4);
    union { unsigned short u[8]; uint4 v; } o;
    o.u[0] = f2bf(f0.x); o.u[1] = f2bf(f0.y); o.u[2] = f2bf(f0.z); o.u[3] = f2bf(f0.w);
    o.u[4] = f2bf(f1.x); o.u[5] = f2bf(f1.y); o.u[6] = f2bf(f1.z); o.u[7] = f2bf(f1.w);
    *(uint4*)(xbf + i) = o.v;
    return;
  }
  const int tb = blockIdx.x - 4096;
  const int bj = tb & 31;  // n block
  const int bi = tb >> 5;  // k block
  {
    const int r0 = t >> 4, c4 = (t & 15) * 4;
#pragma unroll
    for (int p = 0; p < 4; ++p) {
      int r = r0 + p * 16;
      float4 v = *(const float4*)(b + (size_t)(bi * 64 + r) * Hdim + bj * 64 + c4);
      tile[r * 65 + c4 + 0] = f2bf(v.x);
      tile[r * 65 + c4 + 1] = f2bf(v.y);
      tile[r * 65 + c4 + 2] = f2bf(v.z);
      tile[r * 65 + c4 + 3] = f2bf(v.w);
    }
  }
  __syncthreads();
  {
    const int n = t >> 2, kq = (t & 3) * 16;
    union { unsigned short u[16]; uint4 v[2]; } o;
#pragma unroll
    for (int q = 0; q < 16; ++q) o.u[q] = tile[(kq + q) * 65 + n];
    uint4* dst = (uint4*)(bt + (size_t)(bj * 64 + n) * Hdim + bi * 64 + kq);
    dst[0] = o.v[0];
    dst[1] = o.v[1];
  }
}

// ---- GEMM (s = x @ b) with fused windowed-scan epilogue ----
// 128x128 tile, BK=64, 4 waves 2x2 of 64x64 (4x4 frags of 16x16x32 MFMA).
//
// DOUBLE-BUFFERED staging (round 12): issue global_load_lds for tile k+1
// into buffer B, THEN compute tile k from buffer A, THEN one barrier.
// The compiler's vmcnt(0) drain at the barrier now lands after ~620 cyc of
// MFMA has covered the L2 load latency (rounds 5-11 drained BEFORE compute:
// ~41% idle, MfmaUtil pinned ~29%). DMA staging costs zero data-VGPRs
// (round-7's register prefetch spilled 247MB to scratch).
//
// LDS swizzle (BK=64, 3-bit XOR, full permutation of the 8 chunks/row):
// slot (row, chunk c) holds global chunk c ^ (row&7); swizzle applied on
// the global fetch column so the wave-uniform contiguous global_load_lds
// dest is preserved; fragment reads XOR the same term -> conflicts ~0.
//
// XCD swizzle: grid (bm=32 fastest, bn=16) so XCD = bm%8; per-XCD A working
// set 2MB, L2-resident (FETCH 69.7 -> 41.5 MB, r9).
//
// Warm rows: 8 extra A rows (t0-8..t0-1) so the scan warms up in-block
// (|a| <= 0.03125 -> influence of h_{t-8} < 1e-12); warm frag+MFMA on
// waves 0,1 only. Epilogue: acc -> s_tile (136x129 fp32) -> 256 threads
// scan 128 cols x 2 half-chunks -> out. No s buffer in HBM.
__global__ __launch_bounds__(256) void gemm_scan_kernel(const unsigned short* __restrict__ A,
                                                        const unsigned short* __restrict__ Bt,
                                                        const float* __restrict__ a_mat,
                                                        float* __restrict__ out) {
  // alignas(16) REQUIRED: otherwise union alignment is 4 and short8 LDS
  // reads split into 4x ds_read_b32 with 16-way conflicts (round-2: 263 us).
  __shared__ alignas(16) union SM {
    struct {
      unsigned short sA[2][128 * 64];   // 2 x 16 KB
      unsigned short sB[2][128 * 64];   // 2 x 16 KB
      unsigned short sAw[2][8 * 64];    // 2 x 1 KB
    } st;                      // 66 KB
    float s_tile[136 * 129];   // 68.6 KB; [row][col], pad 129
  } sm;

  const int tid = threadIdx.x;
  const int bm = blockIdx.x, bn = blockIdx.y;  // bm fastest -> XCD = bm%8
  const int wave = tid >> 6, lane = tid & 63;
  const int wm = (wave >> 1) * 64, wn = (wave & 1) * 64;
  const int l15 = lane & 15, quad = lane >> 4;
  const int l7 = l15 & 7;  // row&7 of the rows this lane reads fragments from

  // staging: thread tid fills LDS slot (row = tid>>3 + 32c, chunk = tid&7)
  // and fetches global chunk (tid&7)^(row&7); rows advance 32 (0 mod 8) per
  // c-chunk, so the XOR term is constant per thread.
  const int swz = ((tid & 7) ^ ((tid >> 3) & 7)) * 8;
  const unsigned short* aSrc = A + ((size_t)(bm * 128 + (tid >> 3)) * Hdim + swz);
  const unsigned short* bSrc = Bt + ((size_t)(bn * 128 + (tid >> 3)) * Hdim + swz);
  // warm rows staged by wave 3: lane -> row=lane>>3 (8 rows), chunk=lane&7
  const int tw0 = (bm > 0) ? bm * 128 - 8 : 0;  // clamp keeps address valid; bm==0 warm unused
  const int wswz = ((lane & 7) ^ ((lane >> 3) & 7)) * 8;
  const unsigned short* wSrc = A + ((size_t)(tw0 + (lane >> 3)) * Hdim + wswz);

  floatx4 acc[4][4] = {};
  floatx4 accw[4] = {};

  // stage tile (k0) into buffer `buf`
  auto stage = [&](int buf, int k0) {
    unsigned short* aDst = &sm.st.sA[buf][tid * 8];
    unsigned short* bDst = &sm.st.sB[buf][tid * 8];
#pragma unroll
    for (int c = 0; c < 4; ++c)
      load_lds16(aSrc + (size_t)c * 32 * Hdim + k0, aDst + c * 2048);
#pragma unroll
    for (int c = 0; c < 4; ++c)
      load_lds16(bSrc + (size_t)c * 32 * Hdim + k0, bDst + c * 2048);
    if (wave == 3) load_lds16(wSrc + k0, &sm.st.sAw[buf][lane * 8]);
  };

  // compute from buffer `buf`
  auto compute = [&](int buf) {
#pragma unroll
    for (int kk = 0; kk < 64; kk += 32) {
      const int coff = (((kk >> 3) + quad) ^ l7) * 8;
      short8 av[4], bv[4];
#pragma unroll
      for (int i = 0; i < 4; ++i)
        av[i] = lds_read8(&sm.st.sA[buf][(wm + i * 16 + l15) * 64 + coff]);
#pragma unroll
      for (int j = 0; j < 4; ++j)
        bv[j] = lds_read8(&sm.st.sB[buf][(wn + j * 16 + l15) * 64 + coff]);
#pragma unroll
      for (int i = 0; i < 4; ++i)
#pragma unroll
        for (int j = 0; j < 4; ++j)
          acc[i][j] = __builtin_amdgcn_mfma_f32_16x16x32_bf16(av[i], bv[j], acc[i][j], 0, 0, 0);
      if (wave < 2) {  // warm rows: frag read + MFMA on waves 0,1 only
        short8 aw = lds_read8(&sm.st.sAw[buf][l7 * 64 + coff]);
#pragma unroll
        for (int j = 0; j < 4; ++j)
          accw[j] = __builtin_amdgcn_mfma_f32_16x16x32_bf16(aw, bv[j], accw[j], 0, 0, 0);
      }
    }
  };

  // prologue: tile 0 -> buf 0
  stage(0, 0);
  __syncthreads();
  // main loop, unrolled x2 so buffer indices are compile-time
  for (int it = 0; it < 32; it += 2) {
    stage(1, (it + 1) * 64);          // loads in flight during compute
    compute(0);
    __syncthreads();                  // drain lands AFTER compute
    if (it + 2 < 32) stage(0, (it + 2) * 64);
    compute(1);
    __syncthreads();
  }

  // ---- epilogue: registers -> s_tile (C/D layout: col=lane&15, row=quad*4+r) ----
  if (wave < 2 && quad < 2) {  // warm rows idx 0..7 (valid m = 0..7 only)
#pragma unroll
    for (int j = 0; j < 4; ++j)
#pragma unroll
      for (int r = 0; r < 4; ++r)
        sm.s_tile[(quad * 4 + r) * 129 + wn + j * 16 + l15] = accw[j][r];
  }
#pragma unroll
  for (int i = 0; i < 4; ++i)
#pragma unroll
    for (int j = 0; j < 4; ++j)
#pragma unroll
      for (int r = 0; r < 4; ++r)
        sm.s_tile[(8 + wm + i * 16 + quad * 4 + r) * 129 + wn + j * 16 + l15] = acc[i][j][r];
  __syncthreads();

  // ---- windowed scan: 256 threads = 128 cols x 2 half-chunks of 64 rows ----
  const int col = tid & 127;
  const int half = tid >> 7;
  const float aj = a_mat[bn * 128 + col];
  float h = 0.0f;
  const int row0 = 8 + half * 64;
  if (!(bm == 0 && half == 0)) {
#pragma unroll
    for (int r = row0 - 8; r < row0; ++r)  // warm-up (discarded outputs)
      h = tanh_fast(fmaf(aj, h, sm.s_tile[r * 129 + col]));
  }
  const size_t gbase = (size_t)(bm * 128 + half * 64) * Hdim + bn * 128 + col;
#pragma unroll 4
  for (int r2 = 0; r2 < 64; ++r2) {
    h = tanh_fast(fmaf(aj, h, sm.s_tile[(row0 + r2) * 129 + col]));
    out[gbase + (size_t)r2 * Hdim] = h;
  }
}

extern "C" void kernel_launch(void* const* d_in, const int* in_sizes, int n_in,
                              void* d_out, int out_size, void* d_ws, size_t ws_size,
                              hipStream_t stream) {
  const float* x = (const float*)d_in[0];
  const float* a = (const float*)d_in[1];
  const float* b = (const float*)d_in[2];
  float* out = (float*)d_out;

  unsigned short* ws = (unsigned short*)d_ws;
  unsigned short* xbf = ws;                                 // 16.8 MB
  unsigned short* btb = xbf + (size_t)Tdim * Hdim;          // 8.4 MB

  hipLaunchKernelGGL(cvt_kernel, dim3(4096 + (Hdim / 64) * (Hdim / 64)), dim3(256), 0, stream,
                     x, b, xbf, btb);
  // grid: x = bm (32, fastest -> XCD = bm%8), y = bn (16)
  hipLaunchKernelGGL(gemm_scan_kernel, dim3(Tdim / 128, Hdim / 128), dim3(256), 0, stream,
                     xbf, btb, a, out);
}